// Round 2
// baseline (537.730 us; speedup 1.0000x reference)
//
#include <hip/hip_runtime.h>
#include <stdint.h>

// Problem constants
#define DMODEL 1024
#define NHEAD  16
#define DK     64
#define BATCH  4
#define SEQ    2048
#define MTOK   (BATCH * SEQ)   // 8192 token rows

typedef short bf16x8 __attribute__((ext_vector_type(8)));
typedef float f32x4  __attribute__((ext_vector_type(4)));
typedef unsigned short u16x4 __attribute__((ext_vector_type(4)));
typedef unsigned short u16x8 __attribute__((ext_vector_type(8)));

// fp32 -> bf16 (RNE)
static __device__ __forceinline__ unsigned short f2bf(float f) {
    union { float f; unsigned u; } v; v.f = f;
    unsigned r = v.u + 0x7fffu + ((v.u >> 16) & 1u);
    return (unsigned short)(r >> 16);
}

// async global->LDS, 16B per lane. LDS dest is wave-uniform base + lane*16.
static __device__ __forceinline__ void gload_lds16(const void* gsrc, void* lds) {
    __builtin_amdgcn_global_load_lds(
        (__attribute__((address_space(1))) unsigned int*)gsrc,
        (__attribute__((address_space(3))) unsigned int*)lds, 16, 0, 0);
}

static __device__ __forceinline__ f32x4 mfma16(bf16x8 a, bf16x8 b, f32x4 c) {
    return __builtin_amdgcn_mfma_f32_16x16x32_bf16(a, b, c, 0, 0, 0);
}

// ---------------------------------------------------------------------------
// Convert the 4 weight matrices (fp32 [1024,1024]) to bf16 in workspace.
// ---------------------------------------------------------------------------
__global__ __launch_bounds__(256) void cvt_w_kernel(
    const float* __restrict__ w0, const float* __restrict__ w1,
    const float* __restrict__ w2, const float* __restrict__ w3,
    unsigned short* __restrict__ out)
{
    int idx = blockIdx.x * 256 + threadIdx.x;        // 0 .. 1048575
    int a = idx >> 18;                               // which weight (262144 threads each)
    int e = (idx & 0x3FFFF) << 2;                    // element base (4 per thread)
    const float* src = (a == 0) ? w0 : (a == 1) ? w1 : (a == 2) ? w2 : w3;
    float4 v = *(const float4*)(src + e);
    u16x4 o = { f2bf(v.x), f2bf(v.y), f2bf(v.z), f2bf(v.w) };
    *(u16x4*)(out + ((size_t)a << 20) + e) = o;
}

// ---------------------------------------------------------------------------
// 128x128-tile GEMM, C = A @ W^T + bias.   A:[8192,1024]  W:[1024,1024] bf16.
// MODE 0: A fp32 -> C bf16 [8192,1024]                (Q, K projections)
// MODE 1: A fp32 -> C bf16 transposed Vt[b][col][s]   (V projection)
// MODE 2: A bf16 (ws) -> C fp32 [8192,1024]           (output projection)
// m97 structure: BK=32, 4 waves (2x2 of 64x64), 16 MFMA + 8 ds_read_b128/iter.
// ---------------------------------------------------------------------------
template<int MODE>
__global__ __launch_bounds__(256) void gemm128(
    const void* __restrict__ Aany, const unsigned short* __restrict__ Bw,
    const float* __restrict__ bias, void* __restrict__ Cany)
{
    __shared__ __align__(16) unsigned short As[128][32];
    __shared__ __align__(16) unsigned short Bs[128][32];

    const int tid  = threadIdx.x;
    const int lane = tid & 63;
    const int w    = tid >> 6;
    const int wr   = (w >> 1) * 64;
    const int wc   = (w & 1) * 64;
    const int g    = lane >> 4;      // 0..3
    const int q4   = lane & 15;      // 0..15
    const int rowbase = blockIdx.x * 128;
    const int colbase = blockIdx.y * 128;

    f32x4 acc[4][4];
#pragma unroll
    for (int m = 0; m < 4; m++)
#pragma unroll
        for (int n = 0; n < 4; n++) {
            acc[m][n][0] = 0.f; acc[m][n][1] = 0.f;
            acc[m][n][2] = 0.f; acc[m][n][3] = 0.f;
        }

    const int sr = tid >> 1;          // fp32 A staging: row
    const int sc = (tid & 1) * 16;    // fp32 A staging: col group (16 floats)

    for (int k0 = 0; k0 < 1024; k0 += 32) {
        if (MODE <= 1) {
            const float* A = (const float*)Aany;
            const float4* ap = (const float4*)(A + (size_t)(rowbase + sr) * 1024 + k0 + sc);
            float4 v0 = ap[0], v1 = ap[1], v2 = ap[2], v3 = ap[3];
            u16x8 p0 = { f2bf(v0.x), f2bf(v0.y), f2bf(v0.z), f2bf(v0.w),
                         f2bf(v1.x), f2bf(v1.y), f2bf(v1.z), f2bf(v1.w) };
            u16x8 p1 = { f2bf(v2.x), f2bf(v2.y), f2bf(v2.z), f2bf(v2.w),
                         f2bf(v3.x), f2bf(v3.y), f2bf(v3.z), f2bf(v3.w) };
            *(u16x8*)&As[sr][sc]     = p0;
            *(u16x8*)&As[sr][sc + 8] = p1;
        } else {
            const unsigned short* A = (const unsigned short*)Aany;
#pragma unroll
            for (int i = 0; i < 2; i++) {
                int sIdx = i * 256 + w * 64 + lane;
                const unsigned short* src =
                    A + (size_t)(rowbase + (sIdx >> 2)) * 1024 + k0 + (sIdx & 3) * 8;
                gload_lds16(src, &As[0][0] + (size_t)(i * 256 + w * 64) * 8);
            }
        }
#pragma unroll
        for (int i = 0; i < 2; i++) {
            int sIdx = i * 256 + w * 64 + lane;
            const unsigned short* src =
                Bw + (size_t)(colbase + (sIdx >> 2)) * 1024 + k0 + (sIdx & 3) * 8;
            gload_lds16(src, &Bs[0][0] + (size_t)(i * 256 + w * 64) * 8);
        }
        __syncthreads();

        bf16x8 af[4], bfr[4];
#pragma unroll
        for (int m = 0; m < 4; m++) af[m]  = *(const bf16x8*)&As[wr + m * 16 + q4][g * 8];
#pragma unroll
        for (int n = 0; n < 4; n++) bfr[n] = *(const bf16x8*)&Bs[wc + n * 16 + q4][g * 8];
#pragma unroll
        for (int m = 0; m < 4; m++)
#pragma unroll
            for (int n = 0; n < 4; n++)
                acc[m][n] = mfma16(af[m], bfr[n], acc[m][n]);
        __syncthreads();
    }

    // Epilogue. C row = rowbase + wr + m*16 + g*4 + r ; col = colbase + wc + n*16 + q4
#pragma unroll
    for (int n = 0; n < 4; n++) {
        int col = colbase + wc + n * 16 + q4;
        float bv = bias[col];
#pragma unroll
        for (int m = 0; m < 4; m++) {
            int row0 = rowbase + wr + m * 16 + g * 4;
            if (MODE == 0) {
                unsigned short* C = (unsigned short*)Cany;
#pragma unroll
                for (int r = 0; r < 4; r++)
                    C[(size_t)(row0 + r) * 1024 + col] = f2bf(acc[m][n][r] + bv);
            } else if (MODE == 1) {
                // Vt[b][col][s], b = row>>11, s = row&2047; 4 consecutive s.
                unsigned short* C = (unsigned short*)Cany;
                int b = row0 >> 11, s0 = row0 & 2047;
                u16x4 o = { f2bf(acc[m][n][0] + bv), f2bf(acc[m][n][1] + bv),
                            f2bf(acc[m][n][2] + bv), f2bf(acc[m][n][3] + bv) };
                *(u16x4*)(C + ((size_t)((b << 10) + col)) * 2048 + s0) = o;
            } else {
                float* C = (float*)Cany;
#pragma unroll
                for (int r = 0; r < 4; r++)
                    C[(size_t)(row0 + r) * 1024 + col] = acc[m][n][r] + bv;
            }
        }
    }
}

// ---------------------------------------------------------------------------
// Causal flash attention. One block = one (b, h, 64-row q-tile); 4 waves,
// each wave owns 16 q-rows. KVBLK=64. K staged [key][dk] and V staged
// transposed [dk][key], both XOR-swizzled (linear LDS dest, pre-swizzled
// global source; swizzled ds_read).
// ---------------------------------------------------------------------------
__global__ __launch_bounds__(256) void attn_kernel(
    const unsigned short* __restrict__ Q, const unsigned short* __restrict__ K,
    const unsigned short* __restrict__ Vt, unsigned short* __restrict__ ctx)
{
    __shared__ __align__(16) unsigned char KsB[8192];   // [64 key][64 dk] bf16, swizzled
    __shared__ __align__(16) unsigned char VsB[8192];   // [64 dk][64 key] bf16, swizzled
    __shared__ __align__(16) unsigned short Ps[4][16][72]; // per-wave P, stride 72 (144B: 2-way max)

    const int tid  = threadIdx.x;
    const int lane = tid & 63;
    const int w    = tid >> 6;
    const int g    = lane >> 4;
    const int q4   = lane & 15;

    const int bid = blockIdx.x;
    const int qt  = bid & 31;
    const int h   = (bid >> 5) & 15;
    const int b   = bid >> 9;
    const int qb  = qt * 64;

    // Q A-fragments (row = q4, k = g*8 + j), straight from global
    const int qrow = qb + w * 16 + q4;
    const unsigned short* qp = Q + (size_t)(b * 2048 + qrow) * 1024 + h * 64 + g * 8;
    bf16x8 aq0 = *(const bf16x8*)qp;
    bf16x8 aq1 = *(const bf16x8*)(qp + 32);

    f32x4 acc[4];
    float mr[4], lr[4];
#pragma unroll
    for (int d = 0; d < 4; d++) { acc[d][0]=0.f; acc[d][1]=0.f; acc[d][2]=0.f; acc[d][3]=0.f; }
#pragma unroll
    for (int r = 0; r < 4; r++) { mr[r] = -1e30f; lr[r] = 0.f; }

    const int ntiles = qt + 1;
    for (int t = 0; t < ntiles; t++) {
        const int kv0 = t * 64;
        // ---- stage K and Vt tiles (8KB each), pre-swizzled source ----
#pragma unroll
        for (int i = 0; i < 2; i++) {
            int sIdx = i * 256 + w * 64 + lane;
            int rr   = sIdx >> 3;                          // row 0..63
            int cb   = ((sIdx & 7) * 16) ^ ((rr & 7) << 4); // data byte-col in row
            gload_lds16(K + (size_t)(b * 2048 + kv0 + rr) * 1024 + h * 64 + (cb >> 1),
                        KsB + (size_t)(i * 256 + w * 64) * 16);
            gload_lds16(Vt + (size_t)(b * 1024 + h * 64 + rr) * 2048 + kv0 + (cb >> 1),
                        VsB + (size_t)(i * 256 + w * 64) * 16);
        }
        __syncthreads();

        // ---- scores: S = (Q K^T) * 0.125, causal mask ----
        f32x4 sc[4];
#pragma unroll
        for (int st = 0; st < 4; st++) {
            int row = st * 16 + q4;                 // key row in tile
            int sw  = (row & 7) << 4;
            const unsigned char* kb = KsB + row * 128;
            bf16x8 k0 = *(const bf16x8*)(kb + ((g * 16) ^ sw));
            bf16x8 k1 = *(const bf16x8*)(kb + ((g * 16 + 64) ^ sw));
            f32x4 z = { 0.f, 0.f, 0.f, 0.f };
            z = mfma16(aq0, k0, z);
            z = mfma16(aq1, k1, z);
            int key = kv0 + st * 16 + q4;
            int qg  = qb + w * 16 + g * 4;
#pragma unroll
            for (int r = 0; r < 4; r++) {
                float v = z[r] * 0.125f;
                if (key > qg + r) v = -1e9f;
                sc[st][r] = v;
            }
        }

        // ---- online softmax (row reduce across the 16-lane group) ----
        float fac[4];
#pragma unroll
        for (int r = 0; r < 4; r++) {
            float v = fmaxf(fmaxf(sc[0][r], sc[1][r]), fmaxf(sc[2][r], sc[3][r]));
#pragma unroll
            for (int off = 1; off < 16; off <<= 1)
                v = fmaxf(v, __shfl_xor(v, off));
            float mn = fmaxf(mr[r], v);
            fac[r] = __expf(mr[r] - mn);
            mr[r] = mn;
        }
        float rsum[4] = { 0.f, 0.f, 0.f, 0.f };
#pragma unroll
        for (int st = 0; st < 4; st++)
#pragma unroll
            for (int r = 0; r < 4; r++) {
                float p = __expf(sc[st][r] - mr[r]);
                sc[st][r] = p;
                rsum[r] += p;
            }
#pragma unroll
        for (int r = 0; r < 4; r++) {
            float v = rsum[r];
#pragma unroll
            for (int off = 1; off < 16; off <<= 1)
                v += __shfl_xor(v, off);
            lr[r] = lr[r] * fac[r] + v;
            acc[0][r] *= fac[r]; acc[1][r] *= fac[r];
            acc[2][r] *= fac[r]; acc[3][r] *= fac[r];
        }

        // ---- P -> per-wave LDS (transpose to A-frag layout) ----
#pragma unroll
        for (int st = 0; st < 4; st++)
#pragma unroll
            for (int r = 0; r < 4; r++)
                Ps[w][g * 4 + r][st * 16 + q4] = f2bf(sc[st][r]);
        bf16x8 ap0 = *(const bf16x8*)&Ps[w][q4][g * 8];
        bf16x8 ap1 = *(const bf16x8*)&Ps[w][q4][32 + g * 8];

        // ---- PV: acc += P @ V  (B-frags from swizzled Vt tile) ----
#pragma unroll
        for (int dt = 0; dt < 4; dt++) {
            int rowv = dt * 16 + q4;               // dk row
            int swv  = (rowv & 7) << 4;
            const unsigned char* vb = VsB + rowv * 128;
            bf16x8 v0 = *(const bf16x8*)(vb + ((g * 16) ^ swv));
            bf16x8 v1 = *(const bf16x8*)(vb + ((g * 16 + 64) ^ swv));
            acc[dt] = mfma16(ap0, v0, acc[dt]);
            acc[dt] = mfma16(ap1, v1, acc[dt]);
        }
        __syncthreads();
    }

    // ---- normalize and write context (bf16, [b*2048+q][h*64+d]) ----
#pragma unroll
    for (int dt = 0; dt < 4; dt++)
#pragma unroll
        for (int r = 0; r < 4; r++) {
            float o = acc[dt][r] / lr[r];
            int qg = qb + w * 16 + g * 4 + r;
            ctx[(size_t)(b * 2048 + qg) * 1024 + h * 64 + dt * 16 + q4] = f2bf(o);
        }
}

// ---------------------------------------------------------------------------
extern "C" void kernel_launch(void* const* d_in, const int* in_sizes, int n_in,
                              void* d_out, int out_size, void* d_ws, size_t ws_size,
                              hipStream_t stream)
{
    const float* q  = (const float*)d_in[0];
    const float* k  = (const float*)d_in[1];
    const float* v  = (const float*)d_in[2];
    // d_in[3] = causal mask (tril) — handled analytically
    const float* Wq = (const float*)d_in[4];
    const float* bq = (const float*)d_in[5];
    const float* Wk = (const float*)d_in[6];
    const float* bk = (const float*)d_in[7];
    const float* Wv = (const float*)d_in[8];
    const float* bv = (const float*)d_in[9];
    const float* Wo = (const float*)d_in[10];
    const float* bo = (const float*)d_in[11];

    unsigned short* ws   = (unsigned short*)d_ws;
    unsigned short* wq_b = ws;                               // 4 x 1M bf16 weights
    unsigned short* wk_b = ws + (1u << 20);
    unsigned short* wv_b = ws + 2u * (1u << 20);
    unsigned short* wo_b = ws + 3u * (1u << 20);
    unsigned short* Qw   = ws + 4u * (1u << 20);             // [8192,1024] bf16
    unsigned short* Kw   = Qw + (size_t)MTOK * 1024;         // [8192,1024] bf16
    unsigned short* Vt   = Kw + (size_t)MTOK * 1024;         // [4][1024][2048] bf16
    unsigned short* Cx   = Vt + (size_t)MTOK * 1024;         // [8192,1024] bf16

    cvt_w_kernel<<<4096, 256, 0, stream>>>(Wq, Wk, Wv, Wo, wq_b);

    dim3 gg(64, 8);
    gemm128<0><<<gg, 256, 0, stream>>>(q, wq_b, bq, Qw);
    gemm128<0><<<gg, 256, 0, stream>>>(k, wk_b, bk, Kw);
    gemm128<1><<<gg, 256, 0, stream>>>(v, wv_b, bv, Vt);

    attn_kernel<<<2048, 256, 0, stream>>>(Qw, Kw, Vt, Cx);

    gemm128<2><<<gg, 256, 0, stream>>>(Cx, wo_b, bo, d_out);
}

// Round 3
// 476.197 us; speedup vs baseline: 1.1292x; 1.1292x over previous
//
#include <hip/hip_runtime.h>
#include <stdint.h>

// Problem constants
#define DMODEL 1024
#define NHEAD  16
#define DK     64
#define BATCH  4
#define SEQ    2048
#define MTOK   (BATCH * SEQ)   // 8192 token rows

typedef short bf16x8 __attribute__((ext_vector_type(8)));
typedef float f32x4  __attribute__((ext_vector_type(4)));
typedef unsigned short u16x4 __attribute__((ext_vector_type(4)));
typedef unsigned short u16x8 __attribute__((ext_vector_type(8)));

// fp32 -> bf16 (RNE) — used in memory-bound / epilogue paths only
static __device__ __forceinline__ unsigned short f2bf(float f) {
    union { float f; unsigned u; } v; v.f = f;
    unsigned r = v.u + 0x7fffu + ((v.u >> 16) & 1u);
    return (unsigned short)(r >> 16);
}

// raw v_exp_f32: computes 2^x
static __device__ __forceinline__ float exp2_fast(float x) {
    float r;
    asm("v_exp_f32 %0, %1" : "=v"(r) : "v"(x));
    return r;
}

// async global->LDS, 16B per lane. LDS dest is wave-uniform base + lane*16.
static __device__ __forceinline__ void gload_lds16(const void* gsrc, void* lds) {
    __builtin_amdgcn_global_load_lds(
        (__attribute__((address_space(1))) unsigned int*)gsrc,
        (__attribute__((address_space(3))) unsigned int*)lds, 16, 0, 0);
}

static __device__ __forceinline__ f32x4 mfma16(bf16x8 a, bf16x8 b, f32x4 c) {
    return __builtin_amdgcn_mfma_f32_16x16x32_bf16(a, b, c, 0, 0, 0);
}

// ---------------------------------------------------------------------------
// Convert 4 weights (4 x 1M f32) + q,k,v (3 x 8M f32) to bf16 in ws.
// Layout (shorts): [0,4M) W(q,k,v,o); [4M,12M) q; [12M,20M) k; [20M,28M) v.
// Memory-bound; RNE conversion is free here.
// ---------------------------------------------------------------------------
__global__ __launch_bounds__(256) void cvt_all(
    const float* __restrict__ q, const float* __restrict__ k,
    const float* __restrict__ v,
    const float* __restrict__ Wq, const float* __restrict__ Wk,
    const float* __restrict__ Wv, const float* __restrict__ Wo,
    unsigned short* __restrict__ ws)
{
    size_t e = ((size_t)blockIdx.x * 256 + threadIdx.x) * 8;   // 8 f32 / thread
    const float* src;
    if (e < (size_t)(4u << 20)) {
        int a = (int)(e >> 20);
        src = (a == 0 ? Wq : a == 1 ? Wk : a == 2 ? Wv : Wo) + (e & ((1u << 20) - 1));
    } else {
        size_t r = e - (size_t)(4u << 20);
        int which = (int)(r >> 23);
        src = (which == 0 ? q : which == 1 ? k : v) + (r & ((1u << 23) - 1));
    }
    float4 v0 = *(const float4*)src;
    float4 v1 = *(const float4*)(src + 4);
    u16x8 o = { f2bf(v0.x), f2bf(v0.y), f2bf(v0.z), f2bf(v0.w),
                f2bf(v1.x), f2bf(v1.y), f2bf(v1.z), f2bf(v1.w) };
    *(u16x8*)(ws + e) = o;
}

// ---------------------------------------------------------------------------
// 128x128-tile GEMM, C = A @ W^T + bias. A, W bf16 (both via global_load_lds).
// MODE 0: C bf16 [8192,1024]               (Q, K projections)
// MODE 1: C bf16 transposed Vt[b][col][s]  (V projection)
// MODE 2: C fp32 [8192,1024]               (output projection)
// m97 structure: BK=32, 4 waves (2x2 of 64x64), 16 MFMA + 8 ds_read_b128/iter.
// ---------------------------------------------------------------------------
template<int MODE>
__global__ __launch_bounds__(256) void gemm128(
    const unsigned short* __restrict__ A, const unsigned short* __restrict__ Bw,
    const float* __restrict__ bias, void* __restrict__ Cany)
{
    __shared__ __align__(16) unsigned short As[128][32];
    __shared__ __align__(16) unsigned short Bs[128][32];

    const int tid  = threadIdx.x;
    const int lane = tid & 63;
    const int w    = tid >> 6;
    const int wr   = (w >> 1) * 64;
    const int wc   = (w & 1) * 64;
    const int g    = lane >> 4;      // 0..3
    const int q4   = lane & 15;      // 0..15
    const int rowbase = blockIdx.x * 128;
    const int colbase = blockIdx.y * 128;

    f32x4 acc[4][4];
#pragma unroll
    for (int m = 0; m < 4; m++)
#pragma unroll
        for (int n = 0; n < 4; n++) {
            acc[m][n][0] = 0.f; acc[m][n][1] = 0.f;
            acc[m][n][2] = 0.f; acc[m][n][3] = 0.f;
        }

    for (int k0 = 0; k0 < 1024; k0 += 32) {
#pragma unroll
        for (int i = 0; i < 2; i++) {
            int sIdx = i * 256 + w * 64 + lane;
            gload_lds16(A + (size_t)(rowbase + (sIdx >> 2)) * 1024 + k0 + (sIdx & 3) * 8,
                        &As[0][0] + (size_t)(i * 256 + w * 64) * 8);
            gload_lds16(Bw + (size_t)(colbase + (sIdx >> 2)) * 1024 + k0 + (sIdx & 3) * 8,
                        &Bs[0][0] + (size_t)(i * 256 + w * 64) * 8);
        }
        __syncthreads();

        bf16x8 af[4], bfr[4];
#pragma unroll
        for (int m = 0; m < 4; m++) af[m]  = *(const bf16x8*)&As[wr + m * 16 + q4][g * 8];
#pragma unroll
        for (int n = 0; n < 4; n++) bfr[n] = *(const bf16x8*)&Bs[wc + n * 16 + q4][g * 8];
#pragma unroll
        for (int m = 0; m < 4; m++)
#pragma unroll
            for (int n = 0; n < 4; n++)
                acc[m][n] = mfma16(af[m], bfr[n], acc[m][n]);
        __syncthreads();
    }

    // Epilogue. C row = rowbase + wr + m*16 + g*4 + r ; col = colbase + wc + n*16 + q4
#pragma unroll
    for (int n = 0; n < 4; n++) {
        int col = colbase + wc + n * 16 + q4;
        float bv = bias[col];
#pragma unroll
        for (int m = 0; m < 4; m++) {
            int row0 = rowbase + wr + m * 16 + g * 4;
            if (MODE == 0) {
                unsigned short* C = (unsigned short*)Cany;
#pragma unroll
                for (int r = 0; r < 4; r++)
                    C[(size_t)(row0 + r) * 1024 + col] = f2bf(acc[m][n][r] + bv);
            } else if (MODE == 1) {
                // Vt[b][col][s], b = row>>11, s = row&2047; 4 consecutive s.
                unsigned short* C = (unsigned short*)Cany;
                int b = row0 >> 11, s0 = row0 & 2047;
                u16x4 o = { f2bf(acc[m][n][0] + bv), f2bf(acc[m][n][1] + bv),
                            f2bf(acc[m][n][2] + bv), f2bf(acc[m][n][3] + bv) };
                *(u16x4*)(C + ((size_t)((b << 10) + col)) * 2048 + s0) = o;
            } else {
                float* C = (float*)Cany;
#pragma unroll
                for (int r = 0; r < 4; r++)
                    C[(size_t)(row0 + r) * 1024 + col] = acc[m][n][r] + bv;
            }
        }
    }
}

// ---------------------------------------------------------------------------
// Causal flash attention v2. One block = (b, h, 128-row q-tile); 4 waves,
// each wave owns 32 q-rows (2 16-row fragments). KVBLK=64, double-buffered
// K/Vt tiles staged via global_load_lds with XOR-swizzled source (ERRATA#21
// compliant), 2-phase pipeline with counted vmcnt (T3-minimum + m201 idiom).
// Softmax in log2 domain (scale folds 0.125*log2e), defer-max rescale (T13).
// ---------------------------------------------------------------------------
__global__ __launch_bounds__(256, 3) void attn_kernel(
    const unsigned short* __restrict__ Q, const unsigned short* __restrict__ K,
    const unsigned short* __restrict__ Vt, unsigned short* __restrict__ ctx)
{
    __shared__ __align__(16) unsigned char KsB[2][8192];   // [64 key][64 dk] bf16, swizzled
    __shared__ __align__(16) unsigned char VsB[2][8192];   // [64 dk][64 key] bf16, swizzled
    __shared__ __align__(16) unsigned short Ps[4][32][72]; // per-wave P^T->A-frag buffer

    const int tid  = threadIdx.x;
    const int lane = tid & 63;
    const int w    = tid >> 6;
    const int g    = lane >> 4;
    const int q4   = lane & 15;

    const int bid = blockIdx.x;               // 1024 = 4b * 16h * 16qt
    const int qt  = 15 - (bid & 15);          // reversed: big tiles dispatch first
    const int h   = (bid >> 4) & 15;
    const int b   = bid >> 8;
    const int qb  = qt * 128;
    const int qrow0 = qb + w * 32;            // this wave's first q row

    // Q A-fragments for both 16-row fragments, straight from global
    bf16x8 aq[2][2];
#pragma unroll
    for (int f = 0; f < 2; f++) {
        const unsigned short* qp =
            Q + (size_t)(b * 2048 + qrow0 + f * 16 + q4) * 1024 + h * 64 + g * 8;
        aq[f][0] = *(const bf16x8*)qp;
        aq[f][1] = *(const bf16x8*)(qp + 32);
    }

    f32x4 acc[2][4];
    float mr[2][4], lr[2][4];
#pragma unroll
    for (int f = 0; f < 2; f++)
#pragma unroll
        for (int d = 0; d < 4; d++) {
            acc[f][d][0] = 0.f; acc[f][d][1] = 0.f;
            acc[f][d][2] = 0.f; acc[f][d][3] = 0.f;
        }
#pragma unroll
    for (int f = 0; f < 2; f++)
#pragma unroll
        for (int r = 0; r < 4; r++) { mr[f][r] = -1e30f; lr[f][r] = 0.f; }

    const int nt = 2 * qt + 2;

    // stage tile t into buffer bsel (linear LDS dest, inverse-swizzled source)
    auto STAGE = [&](int t, int bsel) {
#pragma unroll
        for (int i = 0; i < 2; i++) {
            int sIdx = i * 256 + w * 64 + lane;
            int rr   = sIdx >> 3;                            // row 0..63
            int cb   = ((sIdx & 7) * 16) ^ ((rr & 7) << 4);  // data byte-col in row
            gload_lds16(K + (size_t)(b * 2048 + t * 64 + rr) * 1024 + h * 64 + (cb >> 1),
                        &KsB[bsel][0] + (size_t)(i * 256 + w * 64) * 16);
            gload_lds16(Vt + (size_t)(b * 1024 + h * 64 + rr) * 2048 + t * 64 + (cb >> 1),
                        &VsB[bsel][0] + (size_t)(i * 256 + w * 64) * 16);
        }
    };

    STAGE(0, 0);
    for (int t = 0; t < nt; t++) {
        const int cur = t & 1;
        if (t + 1 < nt) {
            STAGE(t + 1, cur ^ 1);
            asm volatile("s_waitcnt vmcnt(4)" ::: "memory");   // tile t landed; t+1 in flight
        } else {
            asm volatile("s_waitcnt vmcnt(0)" ::: "memory");
        }
        __builtin_amdgcn_s_barrier();
        __builtin_amdgcn_sched_barrier(0);

        const int kv0 = t * 64;
        if (kv0 <= qrow0 + 31) {               // wave has unmasked work this tile
            // ---- scores (log2 domain): S' = (Q K^T) * 0.125 * log2e ----
            const unsigned char* Kb = &KsB[cur][0];
            f32x4 sc[2][4];
#pragma unroll
            for (int st = 0; st < 4; st++) {
                int row = st * 16 + q4;
                int sw  = (row & 7) << 4;
                bf16x8 k0 = *(const bf16x8*)(Kb + row * 128 + ((g * 16) ^ sw));
                bf16x8 k1 = *(const bf16x8*)(Kb + row * 128 + ((g * 16 + 64) ^ sw));
#pragma unroll
                for (int f = 0; f < 2; f++) {
                    f32x4 z = { 0.f, 0.f, 0.f, 0.f };
                    z = mfma16(aq[f][0], k0, z);
                    z = mfma16(aq[f][1], k1, z);
                    sc[f][st] = z;
                }
            }
            const bool needmask = (kv0 + 63 > qrow0);
            const float SCL = 0.1803368801111204f;   // 0.125 * log2(e)
#pragma unroll
            for (int f = 0; f < 2; f++)
#pragma unroll
                for (int st = 0; st < 4; st++) {
                    int key = kv0 + st * 16 + q4;
                    int qg  = qrow0 + f * 16 + g * 4;
#pragma unroll
                    for (int r = 0; r < 4; r++) {
                        float val = sc[f][st][r] * SCL;
                        if (needmask && key > qg + r) val = -3e8f;
                        sc[f][st][r] = val;
                    }
                }

            // ---- row max (3 fmax + 4 shfl per row) + defer-max test ----
            float pmax[2][4];
            bool resc = false;
#pragma unroll
            for (int f = 0; f < 2; f++)
#pragma unroll
                for (int r = 0; r < 4; r++) {
                    float vmx = fmaxf(fmaxf(sc[f][0][r], sc[f][1][r]),
                                      fmaxf(sc[f][2][r], sc[f][3][r]));
#pragma unroll
                    for (int off = 1; off < 16; off <<= 1)
                        vmx = fmaxf(vmx, __shfl_xor(vmx, off));
                    pmax[f][r] = vmx;
                    resc |= (vmx > mr[f][r] + 11.54f);   // 8 nats in log2
                }
            if (__any(resc)) {
#pragma unroll
                for (int f = 0; f < 2; f++)
#pragma unroll
                    for (int r = 0; r < 4; r++) {
                        float mn  = fmaxf(mr[f][r], pmax[f][r]);
                        float fac = exp2_fast(mr[f][r] - mn);
                        mr[f][r] = mn;
                        lr[f][r] *= fac;
#pragma unroll
                        for (int dt = 0; dt < 4; dt++) acc[f][dt][r] *= fac;
                    }
            }

            // ---- P = exp2(S' - m), row sums, P -> per-wave LDS (trunc bf16) ----
#pragma unroll
            for (int f = 0; f < 2; f++) {
                float rsum[4] = { 0.f, 0.f, 0.f, 0.f };
#pragma unroll
                for (int st = 0; st < 4; st++)
#pragma unroll
                    for (int r = 0; r < 4; r++) {
                        float p = exp2_fast(sc[f][st][r] - mr[f][r]);
                        rsum[r] += p;
                        union { float ff; unsigned u; } cv; cv.ff = p;
                        Ps[w][f * 16 + g * 4 + r][st * 16 + q4] =
                            (unsigned short)(cv.u >> 16);
                    }
#pragma unroll
                for (int r = 0; r < 4; r++) {
                    float s = rsum[r];
#pragma unroll
                    for (int off = 1; off < 16; off <<= 1) s += __shfl_xor(s, off);
                    lr[f][r] += s;
                }
            }

            // ---- PV: acc += P @ V (V-frags shared across both q-fragments) ----
            const unsigned char* Vb = &VsB[cur][0];
            bf16x8 ap[2][2];
#pragma unroll
            for (int f = 0; f < 2; f++) {
                ap[f][0] = *(const bf16x8*)&Ps[w][f * 16 + q4][g * 8];
                ap[f][1] = *(const bf16x8*)&Ps[w][f * 16 + q4][32 + g * 8];
            }
#pragma unroll
            for (int dt = 0; dt < 4; dt++) {
                int rowv = dt * 16 + q4;
                int swv  = (rowv & 7) << 4;
                bf16x8 v0 = *(const bf16x8*)(Vb + rowv * 128 + ((g * 16) ^ swv));
                bf16x8 v1 = *(const bf16x8*)(Vb + rowv * 128 + ((g * 16 + 64) ^ swv));
#pragma unroll
                for (int f = 0; f < 2; f++) {
                    acc[f][dt] = mfma16(ap[f][0], v0, acc[f][dt]);
                    acc[f][dt] = mfma16(ap[f][1], v1, acc[f][dt]);
                }
            }
        }
        asm volatile("s_waitcnt lgkmcnt(0)" ::: "memory");
        __builtin_amdgcn_s_barrier();
    }

    // ---- normalize and write context (bf16, [b*2048+q][h*64+d]) ----
#pragma unroll
    for (int f = 0; f < 2; f++)
#pragma unroll
        for (int dt = 0; dt < 4; dt++)
#pragma unroll
            for (int r = 0; r < 4; r++) {
                float o = acc[f][dt][r] / lr[f][r];
                int qg = qb + w * 32 + f * 16 + g * 4 + r;
                ctx[(size_t)(b * 2048 + qg) * 1024 + h * 64 + dt * 16 + q4] = f2bf(o);
            }
}

// ---------------------------------------------------------------------------
extern "C" void kernel_launch(void* const* d_in, const int* in_sizes, int n_in,
                              void* d_out, int out_size, void* d_ws, size_t ws_size,
                              hipStream_t stream)
{
    const float* q  = (const float*)d_in[0];
    const float* k  = (const float*)d_in[1];
    const float* v  = (const float*)d_in[2];
    // d_in[3] = causal mask (tril) — handled analytically
    const float* Wq = (const float*)d_in[4];
    const float* bq = (const float*)d_in[5];
    const float* Wk = (const float*)d_in[6];
    const float* bk = (const float*)d_in[7];
    const float* Wv = (const float*)d_in[8];
    const float* bv = (const float*)d_in[9];
    const float* Wo = (const float*)d_in[10];
    const float* bo = (const float*)d_in[11];

    const size_t M1 = (size_t)1 << 20;
    unsigned short* ws   = (unsigned short*)d_ws;
    unsigned short* wq_b = ws;                 // [0, 1M)
    unsigned short* wk_b = ws + 1 * M1;        // [1M, 2M)
    unsigned short* wv_b = ws + 2 * M1;        // [2M, 3M)
    unsigned short* wo_b = ws + 3 * M1;        // [3M, 4M)
    unsigned short* qb16 = ws + 4 * M1;        // [4M, 12M)  (later aliased by Vt)
    unsigned short* kb16 = ws + 12 * M1;       // [12M, 20M) (later aliased by Cx)
    unsigned short* vb16 = ws + 20 * M1;       // [20M, 28M)
    unsigned short* Vt   = ws + 4 * M1;        // alias qb16 (dead after gemmQ)
    unsigned short* Cx   = ws + 12 * M1;       // alias kb16 (dead after gemmK)
    unsigned short* Qw   = ws + 28 * M1;       // [28M, 36M)
    unsigned short* Kw   = ws + 36 * M1;       // [36M, 44M)  -> 88 MB total

    cvt_all<<<14336, 256, 0, stream>>>(q, k, v, Wq, Wk, Wv, Wo, ws);

    dim3 gg(64, 8);
    gemm128<0><<<gg, 256, 0, stream>>>(qb16, wq_b, bq, Qw);
    gemm128<0><<<gg, 256, 0, stream>>>(kb16, wk_b, bk, Kw);
    gemm128<1><<<gg, 256, 0, stream>>>(vb16, wv_b, bv, Vt);   // overwrites qb16 region

    attn_kernel<<<1024, 256, 0, stream>>>(Qw, Kw, Vt, Cx);

    gemm128<2><<<gg, 256, 0, stream>>>(Cx, wo_b, bo, d_out);
}